// Round 11
// baseline (138.799 us; speedup 1.0000x reference)
//
#include <hip/hip_runtime.h>
#include <stdint.h>

typedef __attribute__((ext_vector_type(8))) short short8;
typedef __attribute__((ext_vector_type(4))) float f32x4;
typedef __attribute__((ext_vector_type(4))) unsigned int u32x4;
typedef __attribute__((ext_vector_type(4))) unsigned short u16x4;

// B=8, S=2048, D=1024, H=64
// ws (256 MiB): Wb2 bf16 A-frag [12 mt][16 kc][2 ks][64 lane][8] @0 (384 KB)
//   Qw bf16 [16384][64] @393216 ; Kw @2490368 ; Vtw [512][2048] @4587520 ;
//   Op fp32 [4][16384][64] @6684672 ; lp fp32 [4][16384] @40239104 ;
//   Xb bf16 B-frag [1024 nt][16 kc][2 ks][64 lane][8] @40763392 (32 MB)
// R10 AUDIT: launch gaps are ~5us TOTAL (R5 proof) -> qkvf was ~55-60us, the
// elephant. R1's VGPR=56 proves compiler sank the "reg dbuf" loads ->
// serial L2 latency per kk. Fix: hardware-async global_load_lds staging.

__device__ __forceinline__ unsigned short f2bf(float f){
  unsigned int u = __builtin_bit_cast(unsigned int, f);
  u = u + 0x7fffu + ((u >> 16) & 1u);
  return (unsigned short)(u >> 16);
}

typedef const __attribute__((address_space(1))) unsigned int gu32;
typedef __attribute__((address_space(3))) unsigned int lu32;
__device__ __forceinline__ void gld_lds16(const void* g, void* l){
  // HW: writes LDS[l + lane*16] <- global[g(lane)], 16B/lane, async (vmcnt)
  __builtin_amdgcn_global_load_lds((gu32*)g, (lu32*)l, 16, 0, 0);
}

// ---------------- kernel 0: fused W-pack + X-pack (R5-proven).
// blocks 0..8191: X -> bf16 B-frag pack; 8192..8287: W -> A-frag pack.
__global__ __launch_bounds__(256) void pack_k(const float* __restrict__ X,
                                              const float* __restrict__ Wk,
                                              const float* __restrict__ Wq,
                                              const float* __restrict__ Wv,
                                              unsigned short* __restrict__ Xb,
                                              unsigned short* __restrict__ Wb2){
  if (blockIdx.x < 8192){
    const int tid = blockIdx.x * 256 + threadIdx.x;     // 2,097,152 slots
    const int lane = tid & 63, ks = (tid >> 6) & 1, kc = (tid >> 7) & 15, nt = tid >> 11;
    const int row = nt * 16 + (lane & 15);
    const int col = kc * 64 + ks * 32 + (lane >> 4) * 8;
    const float* xp = X + row * 1024 + col;
    f32x4 a = *(const f32x4*)xp;
    f32x4 b = *(const f32x4*)(xp + 4);
    u16x4 lo = { f2bf(a.x), f2bf(a.y), f2bf(a.z), f2bf(a.w) };
    u16x4 hi = { f2bf(b.x), f2bf(b.y), f2bf(b.z), f2bf(b.w) };
    *(u16x4*)(Xb + tid * 8)     = lo;
    *(u16x4*)(Xb + tid * 8 + 4) = hi;
  } else {
    int t = (blockIdx.x - 8192) * 256 + threadIdx.x;
    int e = t * 8;
    int row = e >> 10, col = e & 1023;
    const float* src = (row < 64)  ? (Wq + row * 1024 + col)
                     : (row < 128) ? (Wk + (row - 64) * 1024 + col)
                     :               (Wv + (row - 128) * 1024 + col);
    f32x4 a = *(const f32x4*)src;
    f32x4 b = *(const f32x4*)(src + 4);
    u16x4 lo = { f2bf(a.x), f2bf(a.y), f2bf(a.z), f2bf(a.w) };
    u16x4 hi = { f2bf(b.x), f2bf(b.y), f2bf(b.z), f2bf(b.w) };
    const int mtile = row >> 4, lnn = row & 15;
    const int kchunk = col >> 6, ks = (col >> 5) & 1, qd = (col >> 3) & 3;
    const int lane = qd * 16 + lnn;
    const int off = ((((mtile * 16 + kchunk) * 2 + ks) * 64 + lane)) * 8;
    *(u16x4*)(Wb2 + off)     = lo;
    *(u16x4*)(Wb2 + off + 4) = hi;
  }
}

// ---------------- kernel 1: QKV GEMM with ASYNC LDS staging (global_load_lds).
// grid 256 x 512 (8 waves). Both operands pre-packed in EXACT fragment order
// -> gload_lds is a linear 1KB copy per (wave,chunk). Per kk-step: stage next
// k-slice (24KB W + 8KB X; W chunks c=w,w+8,w+16, X chunk c=w) async ->
// ds_read_b128 frags from current buf -> 12 MFMA/wave -> __syncthreads
// (drains vmcnt+lgkm; stage flight hides under ds+MFMA — m97 2-phase pattern).
// Wave (g=w&3,h=w>>2): A mtiles {3g..3g+2}, B local ntiles {2h,2h+1}.
__global__ __launch_bounds__(512) void qkv3_k(const unsigned short* __restrict__ Xb,
                                              const unsigned short* __restrict__ Wb2,
                                              unsigned short* __restrict__ Qw,
                                              unsigned short* __restrict__ Kw,
                                              unsigned short* __restrict__ Vtw){
  __shared__ unsigned short Wl[2][12288];   // [buf][c=mt*2+ks][lane][8]  24 KB each
  __shared__ unsigned short Xl[2][4096];    // [buf][c=ntl*2+ks][lane][8]  8 KB each
  const int t = threadIdx.x, w = t >> 6, l = t & 63, qd = l >> 4, ln = l & 15;
  const int s0 = blockIdx.x * 64, b = s0 >> 11, sb = s0 & 2047;
  const int g = w & 3, h = w >> 2, mset = g * 3;
  const int nt0g = s0 >> 4;                 // first global ntile of block (4 total)

  f32x4 acc[3][2];
#pragma unroll
  for (int i = 0; i < 3; ++i)
#pragma unroll
    for (int j = 0; j < 2; ++j) acc[i][j] = (f32x4){0.f, 0.f, 0.f, 0.f};

#define STAGE(bi, kkn)                                                         \
  {                                                                            \
    _Pragma("unroll")                                                          \
    for (int cc = 0; cc < 3; ++cc){                                            \
      const int c = w + cc * 8;            /* W chunk 0..23 */                 \
      const int mt_ = c >> 1, ks_ = c & 1;                                     \
      gld_lds16(Wb2 + (((mt_ * 16 + (kkn)) * 2 + ks_) * 64 + l) * 8,           \
                &Wl[bi][c * 512]);                                             \
    }                                                                          \
    {                                                                          \
      const int ntl_ = w >> 1, ks_ = w & 1; /* X chunk = w */                  \
      gld_lds16(Xb + ((((nt0g + ntl_) * 16 + (kkn)) * 2 + ks_) * 64 + l) * 8,  \
                &Xl[bi][w * 512]);                                             \
    }                                                                          \
  }

  STAGE(0, 0)
  __syncthreads();

#pragma unroll
  for (int kk = 0; kk < 16; ++kk){
    const int cur = kk & 1;
    if (kk < 15) STAGE(cur ^ 1, kk + 1)
    short8 af[3][2], bf[2][2];
#pragma unroll
    for (int i = 0; i < 3; ++i)
#pragma unroll
      for (int ks = 0; ks < 2; ++ks)
        af[i][ks] = *(const short8*)&Wl[cur][((mset + i) * 2 + ks) * 512 + l * 8];
#pragma unroll
    for (int j = 0; j < 2; ++j)
#pragma unroll
      for (int ks = 0; ks < 2; ++ks)
        bf[j][ks] = *(const short8*)&Xl[cur][((2 * h + j) * 2 + ks) * 512 + l * 8];
#pragma unroll
    for (int ks = 0; ks < 2; ++ks)
#pragma unroll
      for (int i = 0; i < 3; ++i)
#pragma unroll
        for (int j = 0; j < 2; ++j)
          acc[i][j] = __builtin_amdgcn_mfma_f32_16x16x32_bf16(af[i][ks], bf[j][ks], acc[i][j], 0, 0, 0);
    if (kk < 15) __syncthreads();
  }
#undef STAGE

  // epilogue: D reg r -> hrow = (mset+i)*16 + qd*4 + r, col s = sb + (2h+j)*16 + ln
#pragma unroll
  for (int i = 0; i < 3; ++i){
    const int h0 = (mset + i) * 16 + qd * 4;
#pragma unroll
    for (int j = 0; j < 2; ++j){
      const int s = sb + (2 * h + j) * 16 + ln;
      f32x4 v = acc[i][j];
      u16x4 pk = { f2bf(v.x), f2bf(v.y), f2bf(v.z), f2bf(v.w) };
      if (h0 < 64){
        *(u16x4*)(Qw + (b * 2048 + s) * 64 + h0) = pk;
      } else if (h0 < 128){
        *(u16x4*)(Kw + (b * 2048 + s) * 64 + (h0 - 64)) = pk;
      } else {
        const int hh = h0 - 128;
        Vtw[(b * 64 + hh + 0) * 2048 + s] = pk.x;
        Vtw[(b * 64 + hh + 1) * 2048 + s] = pk.y;
        Vtw[(b * 64 + hh + 2) * 2048 + s] = pk.z;
        Vtw[(b * 64 + hh + 3) * 2048 + s] = pk.w;
      }
    }
  }
}

// ---------------- kernel 2: causal attention, kv-chunked (8 j-steps/chunk).
// EXACT R0/R7-proven version (~20us). (R4: un-staged = 48us; R9: fence = 109us.)
__global__ __launch_bounds__(256) void attn_k(const unsigned short* __restrict__ Qw,
                                              const unsigned short* __restrict__ Kw,
                                              const unsigned short* __restrict__ Vtw,
                                              float* __restrict__ Op,
                                              float* __restrict__ lp){
  __shared__ unsigned short Kl[2][64][72];
  __shared__ unsigned short Vl[2][64][72];
  __shared__ unsigned short Pl[4][16][72];
  const int t = threadIdx.x, w = t >> 6, l = t & 63, qd = l >> 4, ln = l & 15;
  const int b = blockIdx.x & 7;
  const int sp = blockIdx.x >> 3;
  int qi, c;
  if (sp < 32){ qi = 31 - (sp >> 2); c = sp & 3; }
  else if (sp < 56){ int u = sp - 32; int d = u / 3; qi = 23 - d; c = u - d * 3; }
  else if (sp < 72){ int u = sp - 56; qi = 15 - (u >> 1); c = u & 1; }
  else { qi = 7 - (sp - 72); c = 0; }
  const int jbeg = c * 8, jend = min(jbeg + 7, qi);
  const int q0 = b * 2048 + qi * 64, myq = w * 16, rowloc = qd * 4;
  const float c1 = 0.04508422f;                 // log2(e)/32

  short8 aQ[2];
#pragma unroll
  for (int ks = 0; ks < 2; ++ks)
    aQ[ks] = *(const short8*)(Qw + (q0 + myq + ln) * 64 + ks * 32 + qd * 8);

  f32x4 O[4];
#pragma unroll
  for (int i = 0; i < 4; ++i) O[i] = (f32x4){0.f,0.f,0.f,0.f};
  float lacc[4] = {0.f, 0.f, 0.f, 0.f};

  {
    const int kb = b * 2048 + jbeg * 64;
#pragma unroll
    for (int i = 0; i < 2; ++i){
      int cgl = t + i * 256, row = cgl >> 3, sub = cgl & 7;
      *(u32x4*)&Kl[0][row][sub * 8] = *(const u32x4*)(Kw + (kb + row) * 64 + sub * 8);
      *(u32x4*)&Vl[0][row][sub * 8] = *(const u32x4*)(Vtw + (b * 64 + row) * 2048 + jbeg * 64 + sub * 8);
    }
  }

  for (int j = jbeg; j <= jend; ++j){
    __syncthreads();
    const int cur = (j - jbeg) & 1, nxt = cur ^ 1;
    u32x4 kreg[2], vreg[2];
    if (j < jend){
      const int kb = b * 2048 + (j + 1) * 64;
#pragma unroll
      for (int i = 0; i < 2; ++i){
        int cgl = t + i * 256, row = cgl >> 3, sub = cgl & 7;
        kreg[i] = *(const u32x4*)(Kw + (kb + row) * 64 + sub * 8);
        vreg[i] = *(const u32x4*)(Vtw + (b * 64 + row) * 2048 + (j + 1) * 64 + sub * 8);
      }
    }
    f32x4 S[4];
#pragma unroll
    for (int nt = 0; nt < 4; ++nt) S[nt] = (f32x4){0.f,0.f,0.f,0.f};
#pragma unroll
    for (int ks = 0; ks < 2; ++ks)
#pragma unroll
      for (int nt = 0; nt < 4; ++nt){
        short8 bK = *(const short8*)&Kl[cur][nt * 16 + ln][ks * 32 + qd * 8];
        S[nt] = __builtin_amdgcn_mfma_f32_16x16x32_bf16(aQ[ks], bK, S[nt], 0, 0, 0);
      }
    const bool dtile = (j == qi);
#pragma unroll
    for (int nt = 0; nt < 4; ++nt){
      const int cl = nt * 16 + ln;
      f32x4 sv = S[nt];
#pragma unroll
      for (int r = 0; r < 4; ++r){
        float p = __builtin_amdgcn_exp2f(sv[r] * c1);
        if (dtile && cl > myq + rowloc + r) p = 0.f;
        lacc[r] += p;
        Pl[w][rowloc + r][cl] = f2bf(p);
      }
    }
#pragma unroll
    for (int ks = 0; ks < 2; ++ks){
      short8 aP = *(const short8*)&Pl[w][ln][ks * 32 + qd * 8];
#pragma unroll
      for (int ht = 0; ht < 4; ++ht){
        short8 bV = *(const short8*)&Vl[cur][ht * 16 + ln][ks * 32 + qd * 8];
        O[ht] = __builtin_amdgcn_mfma_f32_16x16x32_bf16(aP, bV, O[ht], 0, 0, 0);
      }
    }
    if (j < jend){
#pragma unroll
      for (int i = 0; i < 2; ++i){
        int cgl = t + i * 256, row = cgl >> 3, sub = cgl & 7;
        *(u32x4*)&Kl[nxt][row][sub * 8] = kreg[i];
        *(u32x4*)&Vl[nxt][row][sub * 8] = vreg[i];
      }
    }
  }

  float lred[4];
#pragma unroll
  for (int r = 0; r < 4; ++r){
    float v = lacc[r];
    v += __shfl_xor(v, 1);
    v += __shfl_xor(v, 2);
    v += __shfl_xor(v, 4);
    v += __shfl_xor(v, 8);
    lred[r] = v;
  }
  float* Opc = Op + c * 1048576;
  float* lpc = lp + c * 16384;
#pragma unroll
  for (int r = 0; r < 4; ++r){
    const int rowg = q0 + myq + rowloc + r;
#pragma unroll
    for (int ht = 0; ht < 4; ++ht)
      Opc[rowg * 64 + ht * 16 + ln] = O[ht][r];
    if (ln == 0) lpc[rowg] = lred[r];
  }
}

// ---------------- kernel 3: sum valid chunk partials + normalize (4 chunks max)
__global__ __launch_bounds__(256) void nrm_k(const float* __restrict__ Op,
                                             const float* __restrict__ lp,
                                             float* __restrict__ out){
  const int idx = (blockIdx.x * 256 + threadIdx.x) * 4;
  const int row = idx >> 6;
  const int qi = (row >> 6) & 31;
  const int nch = (qi >> 3) + 1;
  f32x4 s = (f32x4){0.f,0.f,0.f,0.f};
  float lsum = 0.f;
  for (int c = 0; c < nch; ++c){
    f32x4 v = *(const f32x4*)(Op + c * 1048576 + idx);
    s.x += v.x; s.y += v.y; s.z += v.z; s.w += v.w;
    lsum += lp[c * 16384 + row];
  }
  const float inv = 1.0f / lsum;
  s.x *= inv; s.y *= inv; s.z *= inv; s.w *= inv;
  *(f32x4*)(out + idx) = s;
}

extern "C" void kernel_launch(void* const* d_in, const int* in_sizes, int n_in,
                              void* d_out, int out_size, void* d_ws, size_t ws_size,
                              hipStream_t stream){
  const float* X  = (const float*)d_in[0];
  const float* Wk = (const float*)d_in[1];
  const float* Wq = (const float*)d_in[2];
  const float* Wv = (const float*)d_in[3];
  float* out = (float*)d_out;
  char* ws = (char*)d_ws;
  unsigned short* Wb2 = (unsigned short*)(ws);
  unsigned short* Qw  = (unsigned short*)(ws + 393216);
  unsigned short* Kw  = (unsigned short*)(ws + 2490368);
  unsigned short* Vtw = (unsigned short*)(ws + 4587520);
  float* Op = (float*)(ws + 6684672);
  float* lp = (float*)(ws + 40239104);
  unsigned short* Xb  = (unsigned short*)(ws + 40763392);

  hipLaunchKernelGGL(pack_k,  dim3(8288), dim3(256), 0, stream, X, Wk, Wq, Wv, Xb, Wb2);
  hipLaunchKernelGGL(qkv3_k,  dim3(256),  dim3(512), 0, stream, Xb, Wb2, Qw, Kw, Vtw);
  hipLaunchKernelGGL(attn_k,  dim3(640),  dim3(256), 0, stream, Qw, Kw, Vtw, Op, lp);
  hipLaunchKernelGGL(nrm_k,   dim3(1024), dim3(256), 0, stream, Op, lp, out);
}

// Round 13
// 136.845 us; speedup vs baseline: 1.0143x; 1.0143x over previous
//
#include <hip/hip_runtime.h>
#include <stdint.h>

typedef __attribute__((ext_vector_type(8))) short short8;
typedef __attribute__((ext_vector_type(4))) float f32x4;
typedef __attribute__((ext_vector_type(4))) unsigned int u32x4;
typedef __attribute__((ext_vector_type(4))) unsigned short u16x4;

// B=8, S=2048, D=1024, H=64
// ws (256 MiB): Wb2 bf16 A-frag [12 mt][16 kc][2 ks][64 lane][8] @0 (384 KB)
//   Qw bf16 [16384][64] @393216 ; Kw @2490368 ; Vtw [512][2048] @4587520 ;
//   Op fp32 [4][16384][64] @6684672 ; lp fp32 [4][16384] @40239104 ;
//   Xb bf16 B-frag [1024 nt][16 kc][2 ks][64 lane][8] @40763392 (32 MB)
// R12 LESSON (race): STAGE(nxt) before the barrier overwrites the buffer
// other waves still read (WAR). Correct T3/T4 choreography needs TWO raw
// barriers per kk: barrier -> STAGE+vmcnt(4) -> barrier -> ds_read+MFMA.

__device__ __forceinline__ unsigned short f2bf(float f){
  unsigned int u = __builtin_bit_cast(unsigned int, f);
  u = u + 0x7fffu + ((u >> 16) & 1u);
  return (unsigned short)(u >> 16);
}

typedef const __attribute__((address_space(1))) unsigned int gu32;
typedef __attribute__((address_space(3))) unsigned int lu32;
__device__ __forceinline__ void gld_lds16(const void* g, void* l){
  // HW: LDS[base + lane*16] <- global[g(lane)], 16B/lane, async (vmcnt)
  __builtin_amdgcn_global_load_lds((gu32*)g, (lu32*)l, 16, 0, 0);
}

// ---------------- kernel 0: fused W-pack + X-pack (R5-proven).
__global__ __launch_bounds__(256) void pack_k(const float* __restrict__ X,
                                              const float* __restrict__ Wk,
                                              const float* __restrict__ Wq,
                                              const float* __restrict__ Wv,
                                              unsigned short* __restrict__ Xb,
                                              unsigned short* __restrict__ Wb2){
  if (blockIdx.x < 8192){
    const int tid = blockIdx.x * 256 + threadIdx.x;     // 2,097,152 slots
    const int lane = tid & 63, ks = (tid >> 6) & 1, kc = (tid >> 7) & 15, nt = tid >> 11;
    const int row = nt * 16 + (lane & 15);
    const int col = kc * 64 + ks * 32 + (lane >> 4) * 8;
    const float* xp = X + row * 1024 + col;
    f32x4 a = *(const f32x4*)xp;
    f32x4 b = *(const f32x4*)(xp + 4);
    u16x4 lo = { f2bf(a.x), f2bf(a.y), f2bf(a.z), f2bf(a.w) };
    u16x4 hi = { f2bf(b.x), f2bf(b.y), f2bf(b.z), f2bf(b.w) };
    *(u16x4*)(Xb + tid * 8)     = lo;
    *(u16x4*)(Xb + tid * 8 + 4) = hi;
  } else {
    int t = (blockIdx.x - 8192) * 256 + threadIdx.x;
    int e = t * 8;
    int row = e >> 10, col = e & 1023;
    const float* src = (row < 64)  ? (Wq + row * 1024 + col)
                     : (row < 128) ? (Wk + (row - 64) * 1024 + col)
                     :               (Wv + (row - 128) * 1024 + col);
    f32x4 a = *(const f32x4*)src;
    f32x4 b = *(const f32x4*)(src + 4);
    u16x4 lo = { f2bf(a.x), f2bf(a.y), f2bf(a.z), f2bf(a.w) };
    u16x4 hi = { f2bf(b.x), f2bf(b.y), f2bf(b.z), f2bf(b.w) };
    const int mtile = row >> 4, lnn = row & 15;
    const int kchunk = col >> 6, ks = (col >> 5) & 1, qd = (col >> 3) & 3;
    const int lane = qd * 16 + lnn;
    const int off = ((((mtile * 16 + kchunk) * 2 + ks) * 64 + lane)) * 8;
    *(u16x4*)(Wb2 + off)     = lo;
    *(u16x4*)(Wb2 + off + 4) = hi;
  }
}

// ---------------- kernel 1: QKV GEMM, async staging + counted vmcnt,
// RACE-FIXED 2-barrier choreography:
//   barrier#1 (WAR: all waves done reading buf[nxt] at kk-1)
//   STAGE(nxt, kk+1) ; s_waitcnt vmcnt(4)  (own cur loads landed)
//   barrier#2 (RAW: everyone's cur loads visible)
//   ds_read cur ; 12 MFMA/wave
// No full vmcnt drain in-loop. Layout/addressing/MFMA order = R11 (verified).
__global__ __launch_bounds__(512) void qkv5_k(const unsigned short* __restrict__ Xb,
                                              const unsigned short* __restrict__ Wb2,
                                              unsigned short* __restrict__ Qw,
                                              unsigned short* __restrict__ Kw,
                                              unsigned short* __restrict__ Vtw){
  __shared__ unsigned short Wl[2][12288];   // [buf][c=mt*2+ks][lane][8]  24 KB each
  __shared__ unsigned short Xl[2][4096];    // [buf][c=ntl*2+ks][lane][8]  8 KB each
  const int t = threadIdx.x, w = t >> 6, l = t & 63, qd = l >> 4, ln = l & 15;
  const int s0 = blockIdx.x * 64, b = s0 >> 11, sb = s0 & 2047;
  const int g = w & 3, h = w >> 2, mset = g * 3;
  const int nt0g = s0 >> 4;

  f32x4 acc[3][2];
#pragma unroll
  for (int i = 0; i < 3; ++i)
#pragma unroll
    for (int j = 0; j < 2; ++j) acc[i][j] = (f32x4){0.f, 0.f, 0.f, 0.f};

#define STAGE(bi, kkn)                                                         \
  {                                                                            \
    _Pragma("unroll")                                                          \
    for (int cc = 0; cc < 3; ++cc){                                            \
      const int c = w + cc * 8;            /* W chunk 0..23 */                 \
      const int mt_ = c >> 1, ks_ = c & 1;                                     \
      gld_lds16(Wb2 + (((mt_ * 16 + (kkn)) * 2 + ks_) * 64 + l) * 8,           \
                &Wl[bi][c * 512]);                                             \
    }                                                                          \
    {                                                                          \
      const int ntl_ = w >> 1, ks_ = w & 1; /* X chunk = w */                  \
      gld_lds16(Xb + ((((nt0g + ntl_) * 16 + (kkn)) * 2 + ks_) * 64 + l) * 8,  \
                &Xl[bi][w * 512]);                                             \
    }                                                                          \
  }

  STAGE(0, 0)

#pragma unroll
  for (int kk = 0; kk < 16; ++kk){
    const int cur = kk & 1;
    // barrier #1: WAR — everyone finished reading buf[cur^1] (kk-1's cur)
    __builtin_amdgcn_s_barrier();
    asm volatile("" ::: "memory");
    if (kk < 15){
      STAGE(cur ^ 1, kk + 1)
      asm volatile("s_waitcnt vmcnt(4)" ::: "memory");  // own cur loads landed
    } else {
      asm volatile("s_waitcnt vmcnt(0)" ::: "memory");  // final drain (free)
    }
    // barrier #2: RAW — all waves' cur loads visible in LDS
    __builtin_amdgcn_s_barrier();
    asm volatile("" ::: "memory");
    short8 af[3][2], bf[2][2];
#pragma unroll
    for (int i = 0; i < 3; ++i)
#pragma unroll
      for (int ks = 0; ks < 2; ++ks)
        af[i][ks] = *(const short8*)&Wl[cur][((mset + i) * 2 + ks) * 512 + l * 8];
#pragma unroll
    for (int j = 0; j < 2; ++j)
#pragma unroll
      for (int ks = 0; ks < 2; ++ks)
        bf[j][ks] = *(const short8*)&Xl[cur][((2 * h + j) * 2 + ks) * 512 + l * 8];
#pragma unroll
    for (int ks = 0; ks < 2; ++ks)
#pragma unroll
      for (int i = 0; i < 3; ++i)
#pragma unroll
        for (int j = 0; j < 2; ++j)
          acc[i][j] = __builtin_amdgcn_mfma_f32_16x16x32_bf16(af[i][ks], bf[j][ks], acc[i][j], 0, 0, 0);
  }
#undef STAGE

  // epilogue: D reg r -> hrow = (mset+i)*16 + qd*4 + r, col s = sb + (2h+j)*16 + ln
#pragma unroll
  for (int i = 0; i < 3; ++i){
    const int h0 = (mset + i) * 16 + qd * 4;
#pragma unroll
    for (int j = 0; j < 2; ++j){
      const int s = sb + (2 * h + j) * 16 + ln;
      f32x4 v = acc[i][j];
      u16x4 pk = { f2bf(v.x), f2bf(v.y), f2bf(v.z), f2bf(v.w) };
      if (h0 < 64){
        *(u16x4*)(Qw + (b * 2048 + s) * 64 + h0) = pk;
      } else if (h0 < 128){
        *(u16x4*)(Kw + (b * 2048 + s) * 64 + (h0 - 64)) = pk;
      } else {
        const int hh = h0 - 128;
        Vtw[(b * 64 + hh + 0) * 2048 + s] = pk.x;
        Vtw[(b * 64 + hh + 1) * 2048 + s] = pk.y;
        Vtw[(b * 64 + hh + 2) * 2048 + s] = pk.z;
        Vtw[(b * 64 + hh + 3) * 2048 + s] = pk.w;
      }
    }
  }
}

// ---------------- kernel 2: causal attention, kv-chunked (8 j-steps/chunk).
// EXACT R0/R7-proven version (~20us). (R4: un-staged = 48us; R9: fence = 109us.)
__global__ __launch_bounds__(256) void attn_k(const unsigned short* __restrict__ Qw,
                                              const unsigned short* __restrict__ Kw,
                                              const unsigned short* __restrict__ Vtw,
                                              float* __restrict__ Op,
                                              float* __restrict__ lp){
  __shared__ unsigned short Kl[2][64][72];
  __shared__ unsigned short Vl[2][64][72];
  __shared__ unsigned short Pl[4][16][72];
  const int t = threadIdx.x, w = t >> 6, l = t & 63, qd = l >> 4, ln = l & 15;
  const int b = blockIdx.x & 7;
  const int sp = blockIdx.x >> 3;
  int qi, c;
  if (sp < 32){ qi = 31 - (sp >> 2); c = sp & 3; }
  else if (sp < 56){ int u = sp - 32; int d = u / 3; qi = 23 - d; c = u - d * 3; }
  else if (sp < 72){ int u = sp - 56; qi = 15 - (u >> 1); c = u & 1; }
  else { qi = 7 - (sp - 72); c = 0; }
  const int jbeg = c * 8, jend = min(jbeg + 7, qi);
  const int q0 = b * 2048 + qi * 64, myq = w * 16, rowloc = qd * 4;
  const float c1 = 0.04508422f;                 // log2(e)/32

  short8 aQ[2];
#pragma unroll
  for (int ks = 0; ks < 2; ++ks)
    aQ[ks] = *(const short8*)(Qw + (q0 + myq + ln) * 64 + ks * 32 + qd * 8);

  f32x4 O[4];
#pragma unroll
  for (int i = 0; i < 4; ++i) O[i] = (f32x4){0.f,0.f,0.f,0.f};
  float lacc[4] = {0.f, 0.f, 0.f, 0.f};

  {
    const int kb = b * 2048 + jbeg * 64;
#pragma unroll
    for (int i = 0; i < 2; ++i){
      int cgl = t + i * 256, row = cgl >> 3, sub = cgl & 7;
      *(u32x4*)&Kl[0][row][sub * 8] = *(const u32x4*)(Kw + (kb + row) * 64 + sub * 8);
      *(u32x4*)&Vl[0][row][sub * 8] = *(const u32x4*)(Vtw + (b * 64 + row) * 2048 + jbeg * 64 + sub * 8);
    }
  }

  for (int j = jbeg; j <= jend; ++j){
    __syncthreads();
    const int cur = (j - jbeg) & 1, nxt = cur ^ 1;
    u32x4 kreg[2], vreg[2];
    if (j < jend){
      const int kb = b * 2048 + (j + 1) * 64;
#pragma unroll
      for (int i = 0; i < 2; ++i){
        int cgl = t + i * 256, row = cgl >> 3, sub = cgl & 7;
        kreg[i] = *(const u32x4*)(Kw + (kb + row) * 64 + sub * 8);
        vreg[i] = *(const u32x4*)(Vtw + (b * 64 + row) * 2048 + (j + 1) * 64 + sub * 8);
      }
    }
    f32x4 S[4];
#pragma unroll
    for (int nt = 0; nt < 4; ++nt) S[nt] = (f32x4){0.f,0.f,0.f,0.f};
#pragma unroll
    for (int ks = 0; ks < 2; ++ks)
#pragma unroll
      for (int nt = 0; nt < 4; ++nt){
        short8 bK = *(const short8*)&Kl[cur][nt * 16 + ln][ks * 32 + qd * 8];
        S[nt] = __builtin_amdgcn_mfma_f32_16x16x32_bf16(aQ[ks], bK, S[nt], 0, 0, 0);
      }
    const bool dtile = (j == qi);
#pragma unroll
    for (int nt = 0; nt < 4; ++nt){
      const int cl = nt * 16 + ln;
      f32x4 sv = S[nt];
#pragma unroll
      for (int r = 0; r < 4; ++r){
        float p = __builtin_amdgcn_exp2f(sv[r] * c1);
        if (dtile && cl > myq + rowloc + r) p = 0.f;
        lacc[r] += p;
        Pl[w][rowloc + r][cl] = f2bf(p);
      }
    }
#pragma unroll
    for (int ks = 0; ks < 2; ++ks){
      short8 aP = *(const short8*)&Pl[w][ln][ks * 32 + qd * 8];
#pragma unroll
      for (int ht = 0; ht < 4; ++ht){
        short8 bV = *(const short8*)&Vl[cur][ht * 16 + ln][ks * 32 + qd * 8];
        O[ht] = __builtin_amdgcn_mfma_f32_16x16x32_bf16(aP, bV, O[ht], 0, 0, 0);
      }
    }
    if (j < jend){
#pragma unroll
      for (int i = 0; i < 2; ++i){
        int cgl = t + i * 256, row = cgl >> 3, sub = cgl & 7;
        *(u32x4*)&Kl[nxt][row][sub * 8] = kreg[i];
        *(u32x4*)&Vl[nxt][row][sub * 8] = vreg[i];
      }
    }
  }

  float lred[4];
#pragma unroll
  for (int r = 0; r < 4; ++r){
    float v = lacc[r];
    v += __shfl_xor(v, 1);
    v += __shfl_xor(v, 2);
    v += __shfl_xor(v, 4);
    v += __shfl_xor(v, 8);
    lred[r] = v;
  }
  float* Opc = Op + c * 1048576;
  float* lpc = lp + c * 16384;
#pragma unroll
  for (int r = 0; r < 4; ++r){
    const int rowg = q0 + myq + rowloc + r;
#pragma unroll
    for (int ht = 0; ht < 4; ++ht)
      Opc[rowg * 64 + ht * 16 + ln] = O[ht][r];
    if (ln == 0) lpc[rowg] = lred[r];
  }
}

// ---------------- kernel 3: sum valid chunk partials + normalize (4 chunks max)
__global__ __launch_bounds__(256) void nrm_k(const float* __restrict__ Op,
                                             const float* __restrict__ lp,
                                             float* __restrict__ out){
  const int idx = (blockIdx.x * 256 + threadIdx.x) * 4;
  const int row = idx >> 6;
  const int qi = (row >> 6) & 31;
  const int nch = (qi >> 3) + 1;
  f32x4 s = (f32x4){0.f,0.f,0.f,0.f};
  float lsum = 0.f;
  for (int c = 0; c < nch; ++c){
    f32x4 v = *(const f32x4*)(Op + c * 1048576 + idx);
    s.x += v.x; s.y += v.y; s.z += v.z; s.w += v.w;
    lsum += lp[c * 16384 + row];
  }
  const float inv = 1.0f / lsum;
  s.x *= inv; s.y *= inv; s.z *= inv; s.w *= inv;
  *(f32x4*)(out + idx) = s;
}

extern "C" void kernel_launch(void* const* d_in, const int* in_sizes, int n_in,
                              void* d_out, int out_size, void* d_ws, size_t ws_size,
                              hipStream_t stream){
  const float* X  = (const float*)d_in[0];
  const float* Wk = (const float*)d_in[1];
  const float* Wq = (const float*)d_in[2];
  const float* Wv = (const float*)d_in[3];
  float* out = (float*)d_out;
  char* ws = (char*)d_ws;
  unsigned short* Wb2 = (unsigned short*)(ws);
  unsigned short* Qw  = (unsigned short*)(ws + 393216);
  unsigned short* Kw  = (unsigned short*)(ws + 2490368);
  unsigned short* Vtw = (unsigned short*)(ws + 4587520);
  float* Op = (float*)(ws + 6684672);
  float* lp = (float*)(ws + 40239104);
  unsigned short* Xb  = (unsigned short*)(ws + 40763392);

  hipLaunchKernelGGL(pack_k,  dim3(8288), dim3(256), 0, stream, X, Wk, Wq, Wv, Xb, Wb2);
  hipLaunchKernelGGL(qkv5_k,  dim3(256),  dim3(512), 0, stream, Xb, Wb2, Qw, Kw, Vtw);
  hipLaunchKernelGGL(attn_k,  dim3(640),  dim3(256), 0, stream, Qw, Kw, Vtw, Op, lp);
  hipLaunchKernelGGL(nrm_k,   dim3(1024), dim3(256), 0, stream, Op, lp, out);
}

// Round 14
// 127.600 us; speedup vs baseline: 1.0878x; 1.0725x over previous
//
#include <hip/hip_runtime.h>
#include <stdint.h>

typedef __attribute__((ext_vector_type(8))) short short8;
typedef __attribute__((ext_vector_type(4))) float f32x4;
typedef __attribute__((ext_vector_type(4))) unsigned int u32x4;
typedef __attribute__((ext_vector_type(4))) unsigned short u16x4;

// B=8, S=2048, D=1024, H=64
// ws (256 MiB): Wb2 bf16 A-frag [12 mt][16 kc][2 ks][64 lane][8] @0 (384 KB)
//   Qw bf16 [16384][64] @393216 ; Kw @2490368 ; Vtw [512][2048] @4587520 ;
//   Op fp32 [4][16384][64] @6684672 ; lp fp32 [4][16384] @40239104
// SESSION LEDGER: R7 structure = proven optimum (127.95). R9: threadfence
// ticket-fusion = 5x attn regression. R12: stage-before-barrier = WAR race.
// R13: counted-vmcnt correct but packed-Xb family loses to fused qkvf.
// R14: R7 + direct-out for nch==1 attn groups (no fence needed: self-contained).

__device__ __forceinline__ unsigned short f2bf(float f){
  unsigned int u = __builtin_bit_cast(unsigned int, f);
  u = u + 0x7fffu + ((u >> 16) & 1u);
  return (unsigned short)(u >> 16);
}

__device__ __forceinline__ u32x4 pack8(f32x4 a, f32x4 b){
  u32x4 r;
  r.x = (unsigned)f2bf(a.x) | ((unsigned)f2bf(a.y) << 16);
  r.y = (unsigned)f2bf(a.z) | ((unsigned)f2bf(a.w) << 16);
  r.z = (unsigned)f2bf(b.x) | ((unsigned)f2bf(b.y) << 16);
  r.w = (unsigned)f2bf(b.z) | ((unsigned)f2bf(b.w) << 16);
  return r;
}

// ---------------- kernel 0: W -> bf16 A-fragment pack (once; reused by 256 blocks)
__global__ __launch_bounds__(256) void wcvt_k(const float* __restrict__ Wk,
                                              const float* __restrict__ Wq,
                                              const float* __restrict__ Wv,
                                              unsigned short* __restrict__ Wb2){
  int t = blockIdx.x * 256 + threadIdx.x;
  int e = t * 8;
  int row = e >> 10, col = e & 1023;
  const float* src = (row < 64)  ? (Wq + row * 1024 + col)
                   : (row < 128) ? (Wk + (row - 64) * 1024 + col)
                   :               (Wv + (row - 128) * 1024 + col);
  f32x4 a = *(const f32x4*)src;
  f32x4 b = *(const f32x4*)(src + 4);
  u16x4 lo = { f2bf(a.x), f2bf(a.y), f2bf(a.z), f2bf(a.w) };
  u16x4 hi = { f2bf(b.x), f2bf(b.y), f2bf(b.z), f2bf(b.w) };
  const int mtile = row >> 4, lnn = row & 15;
  const int kchunk = col >> 6, ks = (col >> 5) & 1, qd = (col >> 3) & 3;
  const int lane = qd * 16 + lnn;
  const int off = ((((mtile * 16 + kchunk) * 2 + ks) * 64 + lane)) * 8;
  *(u16x4*)(Wb2 + off)     = lo;
  *(u16x4*)(Wb2 + off + 4) = hi;
}

// ---------------- kernel 1: FUSED X-pack + QKV GEMM (EXACT R7-proven config:
// grid 256 x 512, 64-row block, 2-phase 64KB LDS, XOR-swz both sides).
__global__ __launch_bounds__(512) void qkvf_k(const float* __restrict__ X,
                                              const unsigned short* __restrict__ Wb2,
                                              unsigned short* __restrict__ Qw,
                                              unsigned short* __restrict__ Kw,
                                              unsigned short* __restrict__ Vtw){
  __shared__ unsigned short XbL[32768];          // 64 KB: [4 ntl][8 kcl][2 ks][64 lane][8]
  const int t = threadIdx.x, w = t >> 6, l = t & 63, qd = l >> 4, ln = l & 15;
  const int s0 = blockIdx.x * 64, b = s0 >> 11, sb = s0 & 2047;
  const int g = w & 3, h = w >> 2, mset = g * 3;

  f32x4 acc[3][2];
#pragma unroll
  for (int i = 0; i < 3; ++i)
#pragma unroll
    for (int j = 0; j < 2; ++j) acc[i][j] = (f32x4){0.f, 0.f, 0.f, 0.f};

  f32x4 xa[8][2];           // staged X (one phase), fully static indexing
  short8 wreg[2][3][2];     // [buf][mt][ks] W A-frags (global dbuf)

  // issue phase-0 X loads (row = 8i+w fixed per wave; 2KB contiguous per wave)
#pragma unroll
  for (int i = 0; i < 8; ++i){
    const float* xp = X + (s0 + 8 * i + w) * 1024 + l * 8;
    xa[i][0] = *(const f32x4*)xp;
    xa[i][1] = *(const f32x4*)(xp + 4);
  }
  // W prologue (kk=0) while X in flight
#pragma unroll
  for (int i = 0; i < 3; ++i)
#pragma unroll
    for (int ks = 0; ks < 2; ++ks)
      wreg[0][i][ks] = *(const short8*)(Wb2 + ((((mset + i) * 16 + 0) * 2 + ks) * 64 + l) * 8);
  // convert + swizzled LDS write, phase 0
#pragma unroll
  for (int i = 0; i < 8; ++i){
    const int row = 8 * i + w;
    const int ntl = row >> 4;
    const int lane = (row & 15) + 16 * (l & 3);
    const int ks2 = (l >> 2) & 1, kcl = l >> 3;
    int gw = ((ntl * 8 + kcl) * 2 + ks2) * 64 + lane;
    gw ^= (gw >> 4) & 7;
    *(u32x4*)&XbL[gw * 8] = pack8(xa[i][0], xa[i][1]);
  }
  __syncthreads();
  // issue phase-1 X loads now; they complete under phase-0 compute
#pragma unroll
  for (int i = 0; i < 8; ++i){
    const float* xp = X + (s0 + 8 * i + w) * 1024 + 512 + l * 8;
    xa[i][0] = *(const f32x4*)xp;
    xa[i][1] = *(const f32x4*)(xp + 4);
  }
  // ---- phase 0 compute: kk = 0..7
#pragma unroll
  for (int kk = 0; kk < 8; ++kk){
    const int cur = kk & 1, nxt = cur ^ 1;
#pragma unroll
    for (int i = 0; i < 3; ++i)
#pragma unroll
      for (int ks = 0; ks < 2; ++ks)
        wreg[nxt][i][ks] = *(const short8*)(Wb2 + ((((mset + i) * 16 + kk + 1) * 2 + ks) * 64 + l) * 8);
    short8 breg[2][2];
#pragma unroll
    for (int j = 0; j < 2; ++j)
#pragma unroll
      for (int ks = 0; ks < 2; ++ks){
        int gr = (((2 * h + j) * 8 + kk) * 2 + ks) * 64 + l;
        gr ^= (gr >> 4) & 7;
        breg[j][ks] = *(const short8*)&XbL[gr * 8];
      }
#pragma unroll
    for (int ks = 0; ks < 2; ++ks)
#pragma unroll
      for (int i = 0; i < 3; ++i)
#pragma unroll
        for (int j = 0; j < 2; ++j)
          acc[i][j] = __builtin_amdgcn_mfma_f32_16x16x32_bf16(wreg[cur][i][ks], breg[j][ks], acc[i][j], 0, 0, 0);
  }
  __syncthreads();                               // everyone done reading phase-0 tile
  // convert + swizzled LDS write, phase 1
#pragma unroll
  for (int i = 0; i < 8; ++i){
    const int row = 8 * i + w;
    const int ntl = row >> 4;
    const int lane = (row & 15) + 16 * (l & 3);
    const int ks2 = (l >> 2) & 1, kcl = l >> 3;
    int gw = ((ntl * 8 + kcl) * 2 + ks2) * 64 + lane;
    gw ^= (gw >> 4) & 7;
    *(u32x4*)&XbL[gw * 8] = pack8(xa[i][0], xa[i][1]);
  }
  __syncthreads();
  // ---- phase 1 compute: kk = 8..15 (wreg parity continues: kk=8 -> cur=0)
#pragma unroll
  for (int kk = 8; kk < 16; ++kk){
    const int cur = kk & 1, nxt = cur ^ 1;
    if (kk < 15){
#pragma unroll
      for (int i = 0; i < 3; ++i)
#pragma unroll
        for (int ks = 0; ks < 2; ++ks)
          wreg[nxt][i][ks] = *(const short8*)(Wb2 + ((((mset + i) * 16 + kk + 1) * 2 + ks) * 64 + l) * 8);
    }
    short8 breg[2][2];
#pragma unroll
    for (int j = 0; j < 2; ++j)
#pragma unroll
      for (int ks = 0; ks < 2; ++ks){
        int gr = (((2 * h + j) * 8 + (kk & 7)) * 2 + ks) * 64 + l;
        gr ^= (gr >> 4) & 7;
        breg[j][ks] = *(const short8*)&XbL[gr * 8];
      }
#pragma unroll
    for (int ks = 0; ks < 2; ++ks)
#pragma unroll
      for (int i = 0; i < 3; ++i)
#pragma unroll
        for (int j = 0; j < 2; ++j)
          acc[i][j] = __builtin_amdgcn_mfma_f32_16x16x32_bf16(wreg[cur][i][ks], breg[j][ks], acc[i][j], 0, 0, 0);
  }
  // epilogue
#pragma unroll
  for (int i = 0; i < 3; ++i){
    const int h0 = (mset + i) * 16 + qd * 4;
#pragma unroll
    for (int j = 0; j < 2; ++j){
      const int s = sb + (2 * h + j) * 16 + ln;
      f32x4 v = acc[i][j];
      u16x4 pk = { f2bf(v.x), f2bf(v.y), f2bf(v.z), f2bf(v.w) };
      if (h0 < 64){
        *(u16x4*)(Qw + (b * 2048 + s) * 64 + h0) = pk;
      } else if (h0 < 128){
        *(u16x4*)(Kw + (b * 2048 + s) * 64 + (h0 - 64)) = pk;
      } else {
        const int hh = h0 - 128;
        Vtw[(b * 64 + hh + 0) * 2048 + s] = pk.x;
        Vtw[(b * 64 + hh + 1) * 2048 + s] = pk.y;
        Vtw[(b * 64 + hh + 2) * 2048 + s] = pk.z;
        Vtw[(b * 64 + hh + 3) * 2048 + s] = pk.w;
      }
    }
  }
}

// ---------------- kernel 2: causal attention, kv-chunked (8 j-steps/chunk).
// R0/R7-proven core. R14 delta: nch==1 groups (qi<8, 64 of 640 blocks) are
// self-contained -> normalize in-reg and write out DIRECTLY (no partials,
// no fence, no ticket). nch>1 path unchanged (partials + nrm_k).
__global__ __launch_bounds__(256) void attn_k(const unsigned short* __restrict__ Qw,
                                              const unsigned short* __restrict__ Kw,
                                              const unsigned short* __restrict__ Vtw,
                                              float* __restrict__ Op,
                                              float* __restrict__ lp,
                                              float* __restrict__ out){
  __shared__ unsigned short Kl[2][64][72];
  __shared__ unsigned short Vl[2][64][72];
  __shared__ unsigned short Pl[4][16][72];
  const int t = threadIdx.x, w = t >> 6, l = t & 63, qd = l >> 4, ln = l & 15;
  const int b = blockIdx.x & 7;
  const int sp = blockIdx.x >> 3;
  int qi, c;
  if (sp < 32){ qi = 31 - (sp >> 2); c = sp & 3; }
  else if (sp < 56){ int u = sp - 32; int d = u / 3; qi = 23 - d; c = u - d * 3; }
  else if (sp < 72){ int u = sp - 56; qi = 15 - (u >> 1); c = u & 1; }
  else { qi = 7 - (sp - 72); c = 0; }
  const int jbeg = c * 8, jend = min(jbeg + 7, qi);
  const int q0 = b * 2048 + qi * 64, myq = w * 16, rowloc = qd * 4;
  const float c1 = 0.04508422f;                 // log2(e)/32

  short8 aQ[2];
#pragma unroll
  for (int ks = 0; ks < 2; ++ks)
    aQ[ks] = *(const short8*)(Qw + (q0 + myq + ln) * 64 + ks * 32 + qd * 8);

  f32x4 O[4];
#pragma unroll
  for (int i = 0; i < 4; ++i) O[i] = (f32x4){0.f,0.f,0.f,0.f};
  float lacc[4] = {0.f, 0.f, 0.f, 0.f};

  {
    const int kb = b * 2048 + jbeg * 64;
#pragma unroll
    for (int i = 0; i < 2; ++i){
      int cgl = t + i * 256, row = cgl >> 3, sub = cgl & 7;
      *(u32x4*)&Kl[0][row][sub * 8] = *(const u32x4*)(Kw + (kb + row) * 64 + sub * 8);
      *(u32x4*)&Vl[0][row][sub * 8] = *(const u32x4*)(Vtw + (b * 64 + row) * 2048 + jbeg * 64 + sub * 8);
    }
  }

  for (int j = jbeg; j <= jend; ++j){
    __syncthreads();
    const int cur = (j - jbeg) & 1, nxt = cur ^ 1;
    u32x4 kreg[2], vreg[2];
    if (j < jend){
      const int kb = b * 2048 + (j + 1) * 64;
#pragma unroll
      for (int i = 0; i < 2; ++i){
        int cgl = t + i * 256, row = cgl >> 3, sub = cgl & 7;
        kreg[i] = *(const u32x4*)(Kw + (kb + row) * 64 + sub * 8);
        vreg[i] = *(const u32x4*)(Vtw + (b * 64 + row) * 2048 + (j + 1) * 64 + sub * 8);
      }
    }
    f32x4 S[4];
#pragma unroll
    for (int nt = 0; nt < 4; ++nt) S[nt] = (f32x4){0.f,0.f,0.f,0.f};
#pragma unroll
    for (int ks = 0; ks < 2; ++ks)
#pragma unroll
      for (int nt = 0; nt < 4; ++nt){
        short8 bK = *(const short8*)&Kl[cur][nt * 16 + ln][ks * 32 + qd * 8];
        S[nt] = __builtin_amdgcn_mfma_f32_16x16x32_bf16(aQ[ks], bK, S[nt], 0, 0, 0);
      }
    const bool dtile = (j == qi);
#pragma unroll
    for (int nt = 0; nt < 4; ++nt){
      const int cl = nt * 16 + ln;
      f32x4 sv = S[nt];
#pragma unroll
      for (int r = 0; r < 4; ++r){
        float p = __builtin_amdgcn_exp2f(sv[r] * c1);
        if (dtile && cl > myq + rowloc + r) p = 0.f;
        lacc[r] += p;
        Pl[w][rowloc + r][cl] = f2bf(p);
      }
    }
#pragma unroll
    for (int ks = 0; ks < 2; ++ks){
      short8 aP = *(const short8*)&Pl[w][ln][ks * 32 + qd * 8];
#pragma unroll
      for (int ht = 0; ht < 4; ++ht){
        short8 bV = *(const short8*)&Vl[cur][ht * 16 + ln][ks * 32 + qd * 8];
        O[ht] = __builtin_amdgcn_mfma_f32_16x16x32_bf16(aP, bV, O[ht], 0, 0, 0);
      }
    }
    if (j < jend){
#pragma unroll
      for (int i = 0; i < 2; ++i){
        int cgl = t + i * 256, row = cgl >> 3, sub = cgl & 7;
        *(u32x4*)&Kl[nxt][row][sub * 8] = kreg[i];
        *(u32x4*)&Vl[nxt][row][sub * 8] = vreg[i];
      }
    }
  }

  float lred[4];
#pragma unroll
  for (int r = 0; r < 4; ++r){
    float v = lacc[r];
    v += __shfl_xor(v, 1);
    v += __shfl_xor(v, 2);
    v += __shfl_xor(v, 4);
    v += __shfl_xor(v, 8);
    lred[r] = v;
  }

  if (qi < 8){
    // nch==1: self-contained -> normalize in-reg, write out directly.
    // Bit-identical to nrm_k's nch==1 path (O * (1/lred)).
#pragma unroll
    for (int r = 0; r < 4; ++r){
      const int rowg = q0 + myq + rowloc + r;
      const float inv = 1.0f / lred[r];
#pragma unroll
      for (int ht = 0; ht < 4; ++ht)
        out[rowg * 64 + ht * 16 + ln] = O[ht][r] * inv;
    }
    return;
  }

  float* Opc = Op + c * 1048576;
  float* lpc = lp + c * 16384;
#pragma unroll
  for (int r = 0; r < 4; ++r){
    const int rowg = q0 + myq + rowloc + r;
#pragma unroll
    for (int ht = 0; ht < 4; ++ht)
      Opc[rowg * 64 + ht * 16 + ln] = O[ht][r];
    if (ln == 0) lpc[rowg] = lred[r];
  }
}

// ---------------- kernel 3: sum chunk partials + normalize, qi>=8 rows only
// (qi<8 written directly by attn_k). grid 768 x 256: 12288 valid rows x 64 /4.
__global__ __launch_bounds__(256) void nrm_k(const float* __restrict__ Op,
                                             const float* __restrict__ lp,
                                             float* __restrict__ out){
  const int idx4 = (blockIdx.x * 256 + threadIdx.x) * 4;
  const int vrow = idx4 >> 6;                 // 0..12287 (valid-row index)
  const int col  = idx4 & 63;
  const int b    = vrow / 1536;               // 1536 valid rows per batch
  const int rem  = vrow - b * 1536;
  const int qi   = 8 + (rem >> 6);
  const int r    = rem & 63;
  const int row  = b * 2048 + qi * 64 + r;
  const int nch  = (qi >> 3) + 1;             // 2..4
  f32x4 s = (f32x4){0.f,0.f,0.f,0.f};
  float lsum = 0.f;
  for (int c = 0; c < nch; ++c){
    f32x4 v = *(const f32x4*)(Op + c * 1048576 + row * 64 + col);
    s.x += v.x; s.y += v.y; s.z += v.z; s.w += v.w;
    lsum += lp[c * 16384 + row];
  }
  const float inv = 1.0f / lsum;
  s.x *= inv; s.y *= inv; s.z *= inv; s.w *= inv;
  *(f32x4*)(out + row * 64 + col) = s;
}

extern "C" void kernel_launch(void* const* d_in, const int* in_sizes, int n_in,
                              void* d_out, int out_size, void* d_ws, size_t ws_size,
                              hipStream_t stream){
  const float* X  = (const float*)d_in[0];
  const float* Wk = (const float*)d_in[1];
  const float* Wq = (const float*)d_in[2];
  const float* Wv = (const float*)d_in[3];
  float* out = (float*)d_out;
  char* ws = (char*)d_ws;
  unsigned short* Wb2 = (unsigned short*)(ws);
  unsigned short* Qw  = (unsigned short*)(ws + 393216);
  unsigned short* Kw  = (unsigned short*)(ws + 2490368);
  unsigned short* Vtw = (unsigned short*)(ws + 4587520);
  float* Op = (float*)(ws + 6684672);
  float* lp = (float*)(ws + 40239104);

  hipLaunchKernelGGL(wcvt_k,  dim3(96),  dim3(256), 0, stream, Wk, Wq, Wv, Wb2);
  hipLaunchKernelGGL(qkvf_k,  dim3(256), dim3(512), 0, stream, X, Wb2, Qw, Kw, Vtw);
  hipLaunchKernelGGL(attn_k,  dim3(640), dim3(256), 0, stream, Qw, Kw, Vtw, Op, lp, out);
  hipLaunchKernelGGL(nrm_k,   dim3(768), dim3(256), 0, stream, Op, lp, out);
}